// Round 1
// baseline (659.642 us; speedup 1.0000x reference)
//
#include <hip/hip_runtime.h>

typedef float f32x4 __attribute__((ext_vector_type(4)));
typedef __bf16 bf16x8 __attribute__((ext_vector_type(8)));
typedef unsigned short us8 __attribute__((ext_vector_type(8)));
typedef unsigned short us4 __attribute__((ext_vector_type(4)));

#define DIN 448
#define NH 8
#define HD 56
#define MT 64
#define BK 32
#define NTILES 28
#define LDA 40    // padded LDS k-stride (bf16 elems): 2-way-only bank conflicts (free)
#define LDC 456   // padded epilogue tile stride
#define S_LEN 8192

__device__ __forceinline__ unsigned short f2bf(float f) {
  union { float f; unsigned int u; } v; v.f = f;
  unsigned int r = v.u + 0x7fffu + ((v.u >> 16) & 1u);   // RNE
  return (unsigned short)(r >> 16);
}
__device__ __forceinline__ float bf2f(unsigned short h) {
  union { unsigned int u; float f; } v; v.u = ((unsigned int)h) << 16;
  return v.f;
}

// Fold A (suffix-summed), C, B into GT[n=h*56+o][k=i] (bf16, B-transposed layout),
// and convert W (already [n=o][k=i]) to bf16. blocks 0..7: heads; 8..15: W.
__global__ void precompute_kernel(const float* __restrict__ A, const float* __restrict__ B,
                                  const float* __restrict__ C, const float* __restrict__ W,
                                  unsigned short* __restrict__ GT, unsigned short* __restrict__ Wb)
{
  __shared__ float sA[HD * HD], sC[HD * HD], sSA[HD * HD], sD[HD * HD];
  const int tid = threadIdx.x;
  const int blk = blockIdx.x;
  if (blk < 8) {
    const int h = blk;
    for (int i = tid; i < HD * HD; i += 256) { sA[i] = A[h * HD * HD + i]; sC[i] = C[h * HD * HD + i]; }
    __syncthreads();
    // SA[d][e] = sum_{k>=e} A[d][k]   (A @ tril(M))
    for (int i = tid; i < HD * HD; i += 256) {
      int d = i / HD, e = i % HD;
      float s = 0.f;
      for (int k = e; k < HD; ++k) s += sA[d * HD + k];
      sSA[i] = s;
    }
    __syncthreads();
    // D[d][o] = sum_e SA[d][e] * C[o][e]
    for (int i = tid; i < HD * HD; i += 256) {
      int d = i / HD, o = i % HD;
      float s = 0.f;
      for (int e = 0; e < HD; ++e) s += sSA[d * HD + e] * sC[o * HD + e];
      sD[i] = s;
    }
    __syncthreads();
    // GT[h*56+o][i] = sum_d B[h][d][i] * D[d][o]
    for (int i = tid; i < HD * DIN; i += 256) {
      int o = i / DIN, col = i % DIN;
      float s = 0.f;
      for (int dd = 0; dd < HD; ++dd) s += B[(h * HD + dd) * DIN + col] * sD[dd * HD + o];
      GT[(h * HD + o) * DIN + col] = f2bf(s);
    }
  } else {
    const int base = (blk - 8) * (DIN * DIN / 8);
    for (int i = tid; i < DIN * DIN / 8; i += 256) Wb[base + i] = f2bf(W[base + i]);
  }
}

union LdsU {
  struct { unsigned short a[MT * LDA]; unsigned short b[DIN * LDA]; } s;  // 40960 B
  unsigned short c[MT * LDC];                                             // 58368 B
};

// One GEMM structure for both stages. M-tile 64 (4 waves x 16 rows), N=448 full width,
// BK=32 (one 16x16x32 MFMA k-depth). STAGE 1: A = x fp32 (convert on stage),
// epilogue = reshape-scatter + LayerNorm -> yn bf16. STAGE 2: A = yn bf16,
// epilogue = +bias -> out fp32.
template<int STAGE>
__global__ __launch_bounds__(256, 2)
void gemm_stage(const void* __restrict__ Ag, const unsigned short* __restrict__ Bt,
                const float* __restrict__ gamma, const float* __restrict__ beta,
                const float* __restrict__ bias,
                unsigned short* __restrict__ yn, float* __restrict__ out)
{
  __shared__ LdsU lds;
  const int tid  = threadIdx.x;
  const int wave = tid >> 6;
  const int lane = tid & 63;
  const int quad = lane >> 4;
  const int l16  = lane & 15;
  const long row0 = (long)blockIdx.x * MT;

  f32x4 acc[NTILES];
#pragma unroll
  for (int i = 0; i < NTILES; ++i) acc[i] = f32x4{0.f, 0.f, 0.f, 0.f};

  for (int kt = 0; kt < DIN / BK; ++kt) {
    const int k0 = kt * BK;
    __syncthreads();
    if (STAGE == 1) {
      const float* X = (const float*)Ag;
#pragma unroll
      for (int j = 0; j < 2; ++j) {
        int idx = j * 256 + tid;          // 512 float4 loads: 64 rows x 8 chunks
        int r = idx >> 3, c4 = idx & 7;
        const float4 v = *(const float4*)(X + (row0 + r) * DIN + k0 + c4 * 4);
        us4 hv; hv[0] = f2bf(v.x); hv[1] = f2bf(v.y); hv[2] = f2bf(v.z); hv[3] = f2bf(v.w);
        *(us4*)(&lds.s.a[r * LDA + c4 * 4]) = hv;
      }
    } else {
      const unsigned short* Y = (const unsigned short*)Ag;
      int r = tid >> 2, c8 = tid & 3;     // 256 x 16B loads: 64 rows x 4 chunks
      us8 v = *(const us8*)(Y + (row0 + r) * DIN + k0 + c8 * 8);
      *(us8*)(&lds.s.a[r * LDA + c8 * 8]) = v;
    }
    // B tile: 448 rows (n) x 32 k, from n-major global layout
#pragma unroll
    for (int j = 0; j < 7; ++j) {
      int idx = j * 256 + tid;            // 1792 x 16B loads
      int n = idx >> 2, c8 = idx & 3;
      us8 v = *(const us8*)(Bt + (long)n * DIN + k0 + c8 * 8);
      *(us8*)(&lds.s.b[n * LDA + c8 * 8]) = v;
    }
    __syncthreads();
    // A-frag: A[m=l16][k=quad*8+j]; B-frag: B[n=l16][k=quad*8+j] (n-major LDS)
    bf16x8 af = *(const bf16x8*)(&lds.s.a[(wave * 16 + l16) * LDA + quad * 8]);
#pragma unroll
    for (int nt = 0; nt < NTILES; ++nt) {
      bf16x8 bfr = *(const bf16x8*)(&lds.s.b[(nt * 16 + l16) * LDA + quad * 8]);
      acc[nt] = __builtin_amdgcn_mfma_f32_16x16x32_bf16(af, bfr, acc[nt], 0, 0, 0);
    }
  }

  if (STAGE == 2) {
    // C/D layout: row = quad*4+reg, col = l16
    const int mbase = wave * 16 + quad * 4;
#pragma unroll
    for (int nt = 0; nt < NTILES; ++nt) {
      const int col = nt * 16 + l16;
      const float bs = bias[col];
#pragma unroll
      for (int rg = 0; rg < 4; ++rg)
        out[(row0 + mbase + rg) * DIN + col] = acc[nt][rg] + bs;
    }
  } else {
    __syncthreads();   // all waves done reading lds.s before lds.c overwrite
#pragma unroll
    for (int nt = 0; nt < NTILES; ++nt) {
      const int col = nt * 16 + l16;
#pragma unroll
      for (int rg = 0; rg < 4; ++rg)
        lds.c[(wave * 16 + quad * 4 + rg) * LDC + col] = f2bf(acc[nt][rg]);
    }
    __syncthreads();
    // 64 LN rows per block: row_id = g*8 + h; features f=r*56+d come from
    // local s-row g*8+r, col h*56+d. 4 threads per LN row (112 feats each).
    const int row_id = tid >> 2, sub = tid & 3;
    const int g = row_id >> 3, hh = row_id & 7;
    float sum = 0.f, sq = 0.f;
#pragma unroll
    for (int jj = 0; jj < 2; ++jj) {
      const int r = sub * 2 + jj;
#pragma unroll
      for (int d = 0; d < HD; ++d) {
        float v = bf2f(lds.c[(g * 8 + r) * LDC + hh * HD + d]);
        sum += v; sq += v * v;
      }
    }
    sum += __shfl_xor(sum, 1); sq += __shfl_xor(sq, 1);
    sum += __shfl_xor(sum, 2); sq += __shfl_xor(sq, 2);
    const float mean = sum * (1.f / 448.f);
    const float var  = sq * (1.f / 448.f) - mean * mean;
    const float rstd = rsqrtf(var + 1e-5f);
    const long b_idx = row0 >> 13;                    // row0 / 8192
    const int  q0    = (int)((row0 & (S_LEN - 1)) >> 3);
    const long sn    = (long)hh * 1024 + q0 + g;
    unsigned short* dst = yn + ((b_idx << 13) + sn) * DIN;
#pragma unroll
    for (int jj = 0; jj < 2; ++jj) {
      const int r = sub * 2 + jj;
#pragma unroll
      for (int d = 0; d < HD; ++d) {
        const int f = r * HD + d;
        float v = bf2f(lds.c[(g * 8 + r) * LDC + hh * HD + d]);
        v = (v - mean) * rstd * gamma[f] + beta[f];
        dst[f] = f2bf(v);
      }
    }
  }
}

extern "C" void kernel_launch(void* const* d_in, const int* in_sizes, int n_in,
                              void* d_out, int out_size, void* d_ws, size_t ws_size,
                              hipStream_t stream)
{
  const float* x     = (const float*)d_in[0];
  const float* A     = (const float*)d_in[1];
  const float* B     = (const float*)d_in[2];
  const float* C     = (const float*)d_in[3];
  const float* gamma = (const float*)d_in[4];
  const float* beta  = (const float*)d_in[5];
  const float* W     = (const float*)d_in[6];
  const float* bias  = (const float*)d_in[7];
  float* out = (float*)d_out;

  char* ws = (char*)d_ws;
  unsigned short* GT = (unsigned short*)ws;                  // 448*448 bf16
  unsigned short* Wb = (unsigned short*)(ws + 401408);       // 448*448 bf16
  unsigned short* yn = (unsigned short*)(ws + 802816);       // 65536*448 bf16

  precompute_kernel<<<16, 256, 0, stream>>>(A, B, C, W, GT, Wb);
  gemm_stage<1><<<1024, 256, 0, stream>>>(x, GT, gamma, beta, bias, yn, out);
  gemm_stage<2><<<1024, 256, 0, stream>>>(yn, Wb, gamma, beta, bias, yn, out);
}

// Round 2
// 365.313 us; speedup vs baseline: 1.8057x; 1.8057x over previous
//
#include <hip/hip_runtime.h>

typedef float f32x4 __attribute__((ext_vector_type(4)));
typedef __bf16 bf16x8 __attribute__((ext_vector_type(8)));
typedef unsigned short us8 __attribute__((ext_vector_type(8)));
typedef unsigned short us4 __attribute__((ext_vector_type(4)));

#define DIN 448
#define NH 8
#define HD 56
#define MT 64
#define BK 32
#define NTILES 28
#define LDA 40    // padded LDS k-stride (bf16 elems): 2-way-only bank conflicts (free)
#define LDC 456   // padded epilogue tile stride
#define S_LEN 8192

__device__ __forceinline__ unsigned short f2bf(float f) {
  union { float f; unsigned int u; } v; v.f = f;
  unsigned int r = v.u + 0x7fffu + ((v.u >> 16) & 1u);   // RNE
  return (unsigned short)(r >> 16);
}
__device__ __forceinline__ float bf2f(unsigned short h) {
  union { unsigned int u; float f; } v; v.u = ((unsigned int)h) << 16;
  return v.f;
}

// ---------- Precompute, stage A: D[h] = (A[h] @ tril-suffix) @ C[h]^T ----------
// 8 blocks (one per head), all-LDS. ~0.7 MFLOP total.
__global__ void precompute_D(const float* __restrict__ A, const float* __restrict__ C,
                             float* __restrict__ D)
{
  __shared__ float sA[HD * HD], sC[HD * HD], sSA[HD * HD];
  const int h = blockIdx.x, tid = threadIdx.x;
  for (int i = tid; i < HD * HD; i += 256) { sA[i] = A[h * HD * HD + i]; sC[i] = C[h * HD * HD + i]; }
  __syncthreads();
  // SA[d][e] = sum_{k>=e} A[d][k]
  for (int i = tid; i < HD * HD; i += 256) {
    int d = i / HD, e = i % HD;
    float s = 0.f;
    for (int k = e; k < HD; ++k) s += sA[d * HD + k];
    sSA[i] = s;
  }
  __syncthreads();
  // D[d][o] = sum_e SA[d][e] * C[o][e]
  for (int i = tid; i < HD * HD; i += 256) {
    int d = i / HD, o = i % HD;
    float s = 0.f;
    for (int e = 0; e < HD; ++e) s += sSA[d * HD + e] * sC[o * HD + e];
    D[h * HD * HD + i] = s;
  }
}

// ---------- Precompute, stage B: fold B into GT; convert W -> bf16 ----------
// blocks 0..783: GT[h*56+o][col] = sum_d B[h][d][col] * D[h][d][o]  (one thread/output)
// blocks 784..979: Wb = bf16(W), float4-vectorized.
__global__ void precompute_GT(const float* __restrict__ B, const float* __restrict__ D,
                              const float* __restrict__ W,
                              unsigned short* __restrict__ GT, unsigned short* __restrict__ Wb)
{
  const int blk = blockIdx.x, tid = threadIdx.x;
  if (blk < 784) {
    const int g = blk * 256 + tid;          // 200704 outputs
    const int col = g % DIN;
    const int ho  = g / DIN;                // h*56 + o
    const int h = ho / HD, o = ho % HD;
    const float* Bh = B + (long)h * HD * DIN + col;   // B[h][d][col], stride DIN
    const float* Dh = D + h * HD * HD + o;            // D[h][d][o], stride HD
    float s = 0.f;
#pragma unroll
    for (int d = 0; d < HD; ++d) s += Bh[d * DIN] * Dh[d * HD];
    GT[(long)ho * DIN + col] = f2bf(s);
  } else {
    const int g = (blk - 784) * 256 + tid;  // 50176 threads x 4 elems
    const float4 v = *(const float4*)(W + (long)g * 4);
    us4 hv; hv[0] = f2bf(v.x); hv[1] = f2bf(v.y); hv[2] = f2bf(v.z); hv[3] = f2bf(v.w);
    *(us4*)(Wb + (long)g * 4) = hv;
  }
}

union LdsU {
  struct { unsigned short a[MT * LDA]; unsigned short b[DIN * LDA]; } s;  // 40960 B
  unsigned short c[MT * LDC];                                             // 58368 B
};

// One GEMM structure for both stages. M-tile 64 (4 waves x 16 rows), N=448 full width,
// BK=32 (one 16x16x32 MFMA k-depth). STAGE 1: A = x fp32 (convert on stage),
// epilogue = reshape-scatter + LayerNorm -> yn bf16. STAGE 2: A = yn bf16,
// epilogue = +bias -> out fp32.
template<int STAGE>
__global__ __launch_bounds__(256, 2)
void gemm_stage(const void* __restrict__ Ag, const unsigned short* __restrict__ Bt,
                const float* __restrict__ gamma, const float* __restrict__ beta,
                const float* __restrict__ bias,
                unsigned short* __restrict__ yn, float* __restrict__ out)
{
  __shared__ LdsU lds;
  const int tid  = threadIdx.x;
  const int wave = tid >> 6;
  const int lane = tid & 63;
  const int quad = lane >> 4;
  const int l16  = lane & 15;
  const long row0 = (long)blockIdx.x * MT;

  f32x4 acc[NTILES];
#pragma unroll
  for (int i = 0; i < NTILES; ++i) acc[i] = f32x4{0.f, 0.f, 0.f, 0.f};

  for (int kt = 0; kt < DIN / BK; ++kt) {
    const int k0 = kt * BK;
    __syncthreads();
    if (STAGE == 1) {
      const float* X = (const float*)Ag;
#pragma unroll
      for (int j = 0; j < 2; ++j) {
        int idx = j * 256 + tid;          // 512 float4 loads: 64 rows x 8 chunks
        int r = idx >> 3, c4 = idx & 7;
        const float4 v = *(const float4*)(X + (row0 + r) * DIN + k0 + c4 * 4);
        us4 hv; hv[0] = f2bf(v.x); hv[1] = f2bf(v.y); hv[2] = f2bf(v.z); hv[3] = f2bf(v.w);
        *(us4*)(&lds.s.a[r * LDA + c4 * 4]) = hv;
      }
    } else {
      const unsigned short* Y = (const unsigned short*)Ag;
      int r = tid >> 2, c8 = tid & 3;     // 256 x 16B loads: 64 rows x 4 chunks
      us8 v = *(const us8*)(Y + (row0 + r) * DIN + k0 + c8 * 8);
      *(us8*)(&lds.s.a[r * LDA + c8 * 8]) = v;
    }
    // B tile: 448 rows (n) x 32 k, from n-major global layout
#pragma unroll
    for (int j = 0; j < 7; ++j) {
      int idx = j * 256 + tid;            // 1792 x 16B loads
      int n = idx >> 2, c8 = idx & 3;
      us8 v = *(const us8*)(Bt + (long)n * DIN + k0 + c8 * 8);
      *(us8*)(&lds.s.b[n * LDA + c8 * 8]) = v;
    }
    __syncthreads();
    // A-frag: A[m=l16][k=quad*8+j]; B-frag: B[n=l16][k=quad*8+j] (n-major LDS)
    bf16x8 af = *(const bf16x8*)(&lds.s.a[(wave * 16 + l16) * LDA + quad * 8]);
#pragma unroll
    for (int nt = 0; nt < NTILES; ++nt) {
      bf16x8 bfr = *(const bf16x8*)(&lds.s.b[(nt * 16 + l16) * LDA + quad * 8]);
      acc[nt] = __builtin_amdgcn_mfma_f32_16x16x32_bf16(af, bfr, acc[nt], 0, 0, 0);
    }
  }

  if (STAGE == 2) {
    // C/D layout: row = quad*4+reg, col = l16
    const int mbase = wave * 16 + quad * 4;
#pragma unroll
    for (int nt = 0; nt < NTILES; ++nt) {
      const int col = nt * 16 + l16;
      const float bs = bias[col];
#pragma unroll
      for (int rg = 0; rg < 4; ++rg)
        out[(row0 + mbase + rg) * DIN + col] = acc[nt][rg] + bs;
    }
  } else {
    __syncthreads();   // all waves done reading lds.s before lds.c overwrite
#pragma unroll
    for (int nt = 0; nt < NTILES; ++nt) {
      const int col = nt * 16 + l16;
#pragma unroll
      for (int rg = 0; rg < 4; ++rg)
        lds.c[(wave * 16 + quad * 4 + rg) * LDC + col] = f2bf(acc[nt][rg]);
    }
    __syncthreads();
    // 64 LN rows per block: row_id = g*8 + h; features f=r*56+d come from
    // local s-row g*8+r, col h*56+d. 4 threads per LN row (112 feats each).
    const int row_id = tid >> 2, sub = tid & 3;
    const int g = row_id >> 3, hh = row_id & 7;
    float sum = 0.f, sq = 0.f;
#pragma unroll
    for (int jj = 0; jj < 2; ++jj) {
      const int r = sub * 2 + jj;
#pragma unroll
      for (int d = 0; d < HD; ++d) {
        float v = bf2f(lds.c[(g * 8 + r) * LDC + hh * HD + d]);
        sum += v; sq += v * v;
      }
    }
    sum += __shfl_xor(sum, 1); sq += __shfl_xor(sq, 1);
    sum += __shfl_xor(sum, 2); sq += __shfl_xor(sq, 2);
    const float mean = sum * (1.f / 448.f);
    const float var  = sq * (1.f / 448.f) - mean * mean;
    const float rstd = rsqrtf(var + 1e-5f);
    const long b_idx = row0 >> 13;                    // row0 / 8192
    const int  q0    = (int)((row0 & (S_LEN - 1)) >> 3);
    const long sn    = (long)hh * 1024 + q0 + g;
    unsigned short* dst = yn + ((b_idx << 13) + sn) * DIN;
#pragma unroll
    for (int jj = 0; jj < 2; ++jj) {
      const int r = sub * 2 + jj;
#pragma unroll
      for (int d = 0; d < HD; ++d) {
        const int f = r * HD + d;
        float v = bf2f(lds.c[(g * 8 + r) * LDC + hh * HD + d]);
        v = (v - mean) * rstd * gamma[f] + beta[f];
        dst[f] = f2bf(v);
      }
    }
  }
}

extern "C" void kernel_launch(void* const* d_in, const int* in_sizes, int n_in,
                              void* d_out, int out_size, void* d_ws, size_t ws_size,
                              hipStream_t stream)
{
  const float* x     = (const float*)d_in[0];
  const float* A     = (const float*)d_in[1];
  const float* B     = (const float*)d_in[2];
  const float* C     = (const float*)d_in[3];
  const float* gamma = (const float*)d_in[4];
  const float* beta  = (const float*)d_in[5];
  const float* W     = (const float*)d_in[6];
  const float* bias  = (const float*)d_in[7];
  float* out = (float*)d_out;

  char* ws = (char*)d_ws;
  unsigned short* GT = (unsigned short*)ws;                  // 448*448 bf16
  unsigned short* Wb = (unsigned short*)(ws + 401408);       // 448*448 bf16
  unsigned short* yn = (unsigned short*)(ws + 802816);       // 65536*448 bf16
  float* Dws = (float*)(ws + 802816);                        // aliases yn: dead before stage-1

  precompute_D<<<8, 256, 0, stream>>>(A, C, Dws);
  precompute_GT<<<980, 256, 0, stream>>>(B, Dws, W, GT, Wb);
  gemm_stage<1><<<1024, 256, 0, stream>>>(x, GT, gamma, beta, bias, yn, out);
  gemm_stage<2><<<1024, 256, 0, stream>>>(yn, Wb, gamma, beta, bias, yn, out);
}

// Round 4
// 345.057 us; speedup vs baseline: 1.9117x; 1.0587x over previous
//
#include <hip/hip_runtime.h>

typedef float f32x4 __attribute__((ext_vector_type(4)));
typedef __bf16 bf16x8 __attribute__((ext_vector_type(8)));
typedef unsigned short us8 __attribute__((ext_vector_type(8)));
typedef unsigned short us4 __attribute__((ext_vector_type(4)));

#define DIN 448
#define HD 56
#define MT 128     // M tile
#define NT 224     // N tile (2 tiles cover 448; heads 0-3 / 4-7 split cleanly)
#define BK 32
#define KTI (DIN / BK)   // 14
#define LDC 232          // padded C-tile stride (shorts); row stride 464B (16B-aligned)
#define S_LEN 8192

__device__ __forceinline__ unsigned short f2bf(float f) {
  union { float f; unsigned int u; } v; v.f = f;
  unsigned int r = v.u + 0x7fffu + ((v.u >> 16) & 1u);   // RNE
  return (unsigned short)(r >> 16);
}
__device__ __forceinline__ float bf2f(unsigned short h) {
  union { unsigned int u; float f; } v; v.u = ((unsigned int)h) << 16;
  return v.f;
}
__device__ __forceinline__ void gload_lds16(const unsigned short* g, unsigned short* l) {
  __builtin_amdgcn_global_load_lds(
      (const __attribute__((address_space(1))) unsigned int*)g,
      (__attribute__((address_space(3))) unsigned int*)l, 16, 0, 0);
}

// ---------- Precompute A: D[h] = (A[h] @ tril-suffix) @ C[h]^T ----------
__global__ void precompute_D(const float* __restrict__ A, const float* __restrict__ C,
                             float* __restrict__ D)
{
  __shared__ float sA[HD * HD], sC[HD * HD], sSA[HD * HD];
  const int h = blockIdx.x, tid = threadIdx.x;
  for (int i = tid; i < HD * HD; i += 256) { sA[i] = A[h * HD * HD + i]; sC[i] = C[h * HD * HD + i]; }
  __syncthreads();
  for (int i = tid; i < HD * HD; i += 256) {
    int d = i / HD, e = i % HD;
    float s = 0.f;
    for (int k = e; k < HD; ++k) s += sA[d * HD + k];
    sSA[i] = s;
  }
  __syncthreads();
  for (int i = tid; i < HD * HD; i += 256) {
    int d = i / HD, o = i % HD;
    float s = 0.f;
    for (int e = 0; e < HD; ++e) s += sSA[d * HD + e] * sC[o * HD + e];
    D[h * HD * HD + i] = s;
  }
}

// ---------- Precompute B: GT fold + W->bf16 ----------
__global__ void precompute_GT(const float* __restrict__ B, const float* __restrict__ D,
                              const float* __restrict__ W,
                              unsigned short* __restrict__ GT, unsigned short* __restrict__ Wb)
{
  const int blk = blockIdx.x, tid = threadIdx.x;
  if (blk < 784) {
    const int g = blk * 256 + tid;
    const int col = g % DIN;
    const int ho  = g / DIN;
    const int h = ho / HD, o = ho % HD;
    const float* Bh = B + (long)h * HD * DIN + col;
    const float* Dh = D + h * HD * HD + o;
    float s = 0.f;
#pragma unroll
    for (int d = 0; d < HD; ++d) s += Bh[d * DIN] * Dh[d * HD];
    GT[(long)ho * DIN + col] = f2bf(s);
  } else {
    const int g = (blk - 784) * 256 + tid;
    const float4 v = *(const float4*)(W + (long)g * 4);
    us4 hv; hv[0] = f2bf(v.x); hv[1] = f2bf(v.y); hv[2] = f2bf(v.z); hv[3] = f2bf(v.w);
    *(us4*)(Wb + (long)g * 4) = hv;
  }
}

// ---------- Main GEMM: 128x224 tile, 8 waves (4x2), wave = 32x112 ----------
// m97-verified single-buffer two-barrier K-loop: stage -> sync -> compute -> sync.
// Staging via global_load_lds width=16 into unpadded [row][32] LDS layout.
template<int STAGE>
__global__ __launch_bounds__(512, 4)
void gemm_stage(const void* __restrict__ Ag, const unsigned short* __restrict__ Bt,
                const float* __restrict__ gamma, const float* __restrict__ beta,
                const float* __restrict__ bias,
                unsigned short* __restrict__ yn, float* __restrict__ out)
{
  __shared__ union {
    struct { unsigned short a[MT * BK]; unsigned short b[NT * BK]; } s;  // 22528 B
    unsigned short c[MT * LDC];                                          // 59392 B
  } lds;
  const int tid  = threadIdx.x;
  const int wave = tid >> 6;
  const int lane = tid & 63;
  const int quad = lane >> 4;
  const int l16  = lane & 15;
  const int wm   = wave >> 1;       // 0..3 -> 32-row band
  const int wn   = wave & 1;        // 0..1 -> 112-col band
  const int  ntile = blockIdx.x & 1;
  const long mtile = blockIdx.x >> 1;
  const long row0  = mtile * MT;
  const int  nc0   = ntile * NT;

  const int gl_r = lane >> 2;        // row within 16-row group
  const int gl_k = (lane & 3) * 8;   // k offset (shorts)
  const unsigned short* Bt_n = Bt + (long)nc0 * DIN;

  f32x4 acc[2][7];
#pragma unroll
  for (int i = 0; i < 2; ++i)
#pragma unroll
    for (int j = 0; j < 7; ++j) acc[i][j] = f32x4{0.f, 0.f, 0.f, 0.f};

  for (int kt = 0; kt < KTI; ++kt) {
    const int k0 = kt * BK;
    // ---- stage ----
    if (STAGE == 1) {
      const float* X = (const float*)Ag;
      const int r = tid >> 2, q = (tid & 3) * 8;
      const float* p = X + (row0 + r) * DIN + k0 + q;
      const float4 v0 = *(const float4*)(p);
      const float4 v1 = *(const float4*)(p + 4);
      us8 hv;
      hv[0] = f2bf(v0.x); hv[1] = f2bf(v0.y); hv[2] = f2bf(v0.z); hv[3] = f2bf(v0.w);
      hv[4] = f2bf(v1.x); hv[5] = f2bf(v1.y); hv[6] = f2bf(v1.z); hv[7] = f2bf(v1.w);
      *(us8*)(&lds.s.a[r * BK + q]) = hv;
    } else {
      const unsigned short* Y = (const unsigned short*)Ag;
      gload_lds16(Y + (row0 + wave * 16 + gl_r) * DIN + k0 + gl_k,
                  &lds.s.a[wave * 512]);
    }
    gload_lds16(Bt_n + (long)(wave * 16 + gl_r) * DIN + k0 + gl_k,
                &lds.s.b[wave * 512]);
    if (wave < 6)
      gload_lds16(Bt_n + (long)(128 + wave * 16 + gl_r) * DIN + k0 + gl_k,
                  &lds.s.b[4096 + wave * 512]);
    __syncthreads();   // drain vmcnt (LDS-DMA) + lgkm, all tiles visible
    // ---- compute ----
    {
      const bf16x8 af0 = *(const bf16x8*)(&lds.s.a[(wm * 32 + l16) * BK + quad * 8]);
      const bf16x8 af1 = *(const bf16x8*)(&lds.s.a[(wm * 32 + 16 + l16) * BK + quad * 8]);
#pragma unroll
      for (int j = 0; j < 7; ++j) {
        const bf16x8 bfr = *(const bf16x8*)(&lds.s.b[(wn * 112 + j * 16 + l16) * BK + quad * 8]);
        acc[0][j] = __builtin_amdgcn_mfma_f32_16x16x32_bf16(af0, bfr, acc[0][j], 0, 0, 0);
        acc[1][j] = __builtin_amdgcn_mfma_f32_16x16x32_bf16(af1, bfr, acc[1][j], 0, 0, 0);
      }
    }
    __syncthreads();   // all reads done before next stage overwrites
  }

  if (STAGE == 2) {
    // C/D: row = quad*4+rg, col = l16
#pragma unroll
    for (int j = 0; j < 7; ++j) {
      const int col = nc0 + wn * 112 + j * 16 + l16;
      const float bs = bias[col];
#pragma unroll
      for (int i = 0; i < 2; ++i)
#pragma unroll
        for (int rg = 0; rg < 4; ++rg)
          out[(row0 + wm * 32 + i * 16 + quad * 4 + rg) * DIN + col] = acc[i][j][rg] + bs;
    }
  } else {
    // K-loop ended with a barrier: staging buf dead, safe to write lds.c
#pragma unroll
    for (int i = 0; i < 2; ++i)
#pragma unroll
      for (int j = 0; j < 7; ++j) {
        const int col  = wn * 112 + j * 16 + l16;
        const int rowb = wm * 32 + i * 16 + quad * 4;
#pragma unroll
        for (int rg = 0; rg < 4; ++rg)
          lds.c[(rowb + rg) * LDC + col] = f2bf(acc[i][j][rg]);
      }
    __syncthreads();
    // 64 LN rows (16 q-groups x 4 heads of this ntile); 8 threads/row (sub = r).
    // Pass 1: sum/sq. Pass 2: normalize + store (no big live array -> no spill).
    const int row_id = tid >> 3, sub = tid & 7;
    const int g = row_id >> 2, hl = row_id & 3;
    const unsigned short* src = &lds.c[(g * 8 + sub) * LDC + hl * HD];
    float sum = 0.f, sq = 0.f;
#pragma unroll
    for (int c = 0; c < 7; ++c) {
      const us8 u = *(const us8*)(src + c * 8);
#pragma unroll
      for (int e = 0; e < 8; ++e) { const float f = bf2f(u[e]); sum += f; sq += f * f; }
    }
    sum += __shfl_xor(sum, 1); sq += __shfl_xor(sq, 1);
    sum += __shfl_xor(sum, 2); sq += __shfl_xor(sq, 2);
    sum += __shfl_xor(sum, 4); sq += __shfl_xor(sq, 4);
    const float mean = sum * (1.f / 448.f);
    const float rstd = rsqrtf(sq * (1.f / 448.f) - mean * mean + 1e-5f);
    const int  hh    = ntile * 4 + hl;
    const long q0    = (row0 & (S_LEN - 1)) >> 3;
    const long b_idx = row0 >> 13;
    unsigned short* dst = yn + ((b_idx << 13) + (long)hh * 1024 + q0 + g) * DIN + sub * HD;
    const float* gp = gamma + sub * HD;
    const float* bp = beta  + sub * HD;
#pragma unroll
    for (int c = 0; c < 7; ++c) {
      const us8 u = *(const us8*)(src + c * 8);
      const float4 g0 = *(const float4*)(gp + c * 8);
      const float4 g1 = *(const float4*)(gp + c * 8 + 4);
      const float4 b0 = *(const float4*)(bp + c * 8);
      const float4 b1 = *(const float4*)(bp + c * 8 + 4);
      us8 o;
      o[0] = f2bf((bf2f(u[0]) - mean) * rstd * g0.x + b0.x);
      o[1] = f2bf((bf2f(u[1]) - mean) * rstd * g0.y + b0.y);
      o[2] = f2bf((bf2f(u[2]) - mean) * rstd * g0.z + b0.z);
      o[3] = f2bf((bf2f(u[3]) - mean) * rstd * g0.w + b0.w);
      o[4] = f2bf((bf2f(u[4]) - mean) * rstd * g1.x + b1.x);
      o[5] = f2bf((bf2f(u[5]) - mean) * rstd * g1.y + b1.y);
      o[6] = f2bf((bf2f(u[6]) - mean) * rstd * g1.z + b1.z);
      o[7] = f2bf((bf2f(u[7]) - mean) * rstd * g1.w + b1.w);
      *(us8*)(dst + c * 8) = o;
    }
  }
}

extern "C" void kernel_launch(void* const* d_in, const int* in_sizes, int n_in,
                              void* d_out, int out_size, void* d_ws, size_t ws_size,
                              hipStream_t stream)
{
  const float* x     = (const float*)d_in[0];
  const float* A     = (const float*)d_in[1];
  const float* B     = (const float*)d_in[2];
  const float* C     = (const float*)d_in[3];
  const float* gamma = (const float*)d_in[4];
  const float* beta  = (const float*)d_in[5];
  const float* W     = (const float*)d_in[6];
  const float* bias  = (const float*)d_in[7];
  float* out = (float*)d_out;

  char* ws = (char*)d_ws;
  unsigned short* GT = (unsigned short*)ws;                  // 448*448 bf16
  unsigned short* Wb = (unsigned short*)(ws + 401408);       // 448*448 bf16
  unsigned short* yn = (unsigned short*)(ws + 802816);       // 65536*448 bf16
  float* Dws = (float*)(ws + 802816);                        // aliases yn (dead before stage-1)

  precompute_D<<<8, 256, 0, stream>>>(A, C, Dws);
  precompute_GT<<<980, 256, 0, stream>>>(B, Dws, W, GT, Wb);
  gemm_stage<1><<<1024, 512, 0, stream>>>(x, GT, gamma, beta, bias, yn, out);
  gemm_stage<2><<<1024, 512, 0, stream>>>(yn, Wb, gamma, beta, bias, yn, out);
}